// Round 11
// baseline (666.988 us; speedup 1.0000x reference)
//
#include <hip/hip_runtime.h>
#include <hip/hip_bf16.h>
#include <math.h>

// B=8192, D=512, V=64, E=8, hidden (1024,512,256)
// All matmuls as bf16 MFMA with hi/lo split (3 products):
//   C = Ahi*Bhi + Alo*Bhi + Ahi*Blo.  A: [M][2K] hi|lo, Bt: [N][2K] hi|lo.
// Round 11: intensity over geometry — 256x128 tile, 512 threads (8 waves of
// 64x64, same per-wave VGPR as R10), 50KB LDS -> 3 blocks/CU, 24 waves/CU.
// 131 FLOP per staged byte (+36% vs 128x128). Same proven 2-barrier K-step.

typedef short bf16x8 __attribute__((ext_vector_type(8)));
typedef float f32x4 __attribute__((ext_vector_type(4)));

#define AS1 __attribute__((address_space(1)))
#define AS3 __attribute__((address_space(3)))
#define SCHED0 __builtin_amdgcn_sched_barrier(0)
#define SBAR __builtin_amdgcn_s_barrier()

__device__ __forceinline__ ushort f2bf(float x){
  union { float f; unsigned u; } v; v.f = x;
  unsigned r = v.u + 0x7fffu + ((v.u >> 16) & 1u);
  return (ushort)(r >> 16);
}
__device__ __forceinline__ float bf2f(ushort h){
  union { unsigned u; float f; } v; v.u = ((unsigned)h) << 16; return v.f;
}
__device__ __forceinline__ float elu_f(float x){
  return x > 0.f ? x : __expf(x) - 1.f;
}

// ---- unified prep: activations ----
struct AJob { const float* X; ushort* A; int total, K; };
__global__ void prep_act_all(AJob j0, AJob j1, int t0){
  int i = blockIdx.x * 256 + threadIdx.x;
  AJob J; int idx;
  if (i < t0){ J = j0; idx = i; }
  else { J = j1; idx = i - t0; if (idx >= J.total) return; }
  int row = idx / J.K, k = idx - row * J.K;
  float x = J.X[idx];
  ushort hi = f2bf(x);
  ushort lo = f2bf(x - bf2f(hi));
  size_t base = (size_t)row * (size_t)(2 * J.K);
  J.A[base + k] = hi;
  J.A[base + J.K + k] = lo;
}

// ---- unified prep: weights f32 [E][K][N] -> [E][N][2K] bf16 hi|lo ----
struct WJob { const float* W; ushort* Bt; int K, N, nb, nk, blkStart; };
struct WJobs { WJob j[6]; int njobs; };
__global__ void prep_w_all(WJobs jobs){
  __shared__ float tile[32][33];
  int b = blockIdx.x;
  int ji = 0;
  while (ji + 1 < jobs.njobs && b >= jobs.j[ji + 1].blkStart) ji++;
  WJob J = jobs.j[ji];
  int rem = b - J.blkStart;
  int x = rem % J.nb; rem /= J.nb;
  int y = rem % J.nk; int e = rem / J.nk;
  const float* w = J.W + (size_t)e * J.K * J.N;
  ushort* bt = J.Bt + (size_t)e * J.N * 2 * J.K;
  int n0 = x * 32, k0 = y * 32;
  for (int i = threadIdx.y; i < 32; i += 8)
    tile[i][threadIdx.x] = w[(size_t)(k0 + i) * J.N + n0 + threadIdx.x];
  __syncthreads();
  for (int jj = threadIdx.y; jj < 32; jj += 8){
    float v = tile[threadIdx.x][jj];
    ushort hi = f2bf(v);
    ushort lo = f2bf(v - bf2f(hi));
    size_t base = (size_t)(n0 + jj) * (size_t)(2 * J.K);
    bt[base + k0 + threadIdx.x] = hi;
    bt[base + J.K + k0 + threadIdx.x] = lo;
  }
}

// ---- descriptor-batched 256x128 GEMM, interleaved hi|lo 32-k steps ----
// mode 0: C = split bf16 [M][2N]; mode 1: C = f32 [M][N];
// mode 2: no C — ret[bx][row][eidx] = sum over THIS col-half of elu(acc+bias)*w3
struct Slice {
  const ushort* A; const ushort* Bt; const float* bias; void* C;
  const float* w3; const float* rbp; float* ret;
  int N, K, log2gx, mode, blkStart, eidx;
};
struct SliceArr { Slice s[9]; int nz; };

__global__ __launch_bounds__(512, 3) void gemm8p(SliceArr args){
  // tile cols 0..31 = hi k0..31, cols 32..63 = lo k0..31
  __shared__ __align__(16) ushort As[256][64];   // 32KB (rows)
  __shared__ __align__(16) ushort Bs[128][64];   // 16KB (cols)
  __shared__ float red[2][256];                  // 2KB (mode-2 reduce)

  // XCD-chunked bijective swizzle (grids here are multiples of 8)
  const int nwg  = gridDim.x;
  const int orig = blockIdx.x;
  const int wg   = (orig & 7) * (nwg >> 3) + (orig >> 3);

  int z = 0;
  while (z + 1 < args.nz && wg >= args.s[z + 1].blkStart) z++;
  const Slice sl = args.s[z];
  const int rem = wg - sl.blkStart;
  const int gxm = (1 << sl.log2gx) - 1;
  const int bx  = rem & gxm;
  const int by  = rem >> sl.log2gx;

  const ushort* __restrict__ Ag = sl.A;
  const ushort* __restrict__ Bg = sl.Bt;
  const int K = sl.K;

  const int tid  = threadIdx.x;
  const int lane = tid & 63;
  const int wave = tid >> 6;                    // 0..7
  const int wrow = wave >> 1;                   // 0..3 : rows wrow*64..+63
  const int wc   = wave & 1;                    // 0..1 : cols wc*64..+63
  const int rowBase = by * 256;
  const int colBase = bx * 128;
  const int KB = K >> 5;                        // 32-k steps
  const int lr = lane & 15;
  const int lk = (lane >> 4) << 3;
  const int swzR = (lr & 7) << 3;
  const size_t strideK2 = (size_t)(2 * K);

  const int rowS = tid >> 3;                    // 0..63
  const int swzS = ((tid >> 3) & 7) << 3;
  const int colS = ((tid & 7) << 3) ^ swzS;     // 0..63 combined col (kind in bit 5)

  // stage A (4 layers) + B (2 layers) of 32-k step kt (6 instrs/thread, 48KB)
  auto stage = [&](int kt){
    int tt = (kt < KB) ? kt : (KB - 1);         // clamp: dead-but-safe
    int kA = ((colS & 32) ? K : 0) + (tt << 5) + (colS & 31);
    {
      char* lb = (char*)&As[0][0];
      #pragma unroll
      for (int j = 0; j < 4; j++){
        const ushort* src = Ag + (size_t)(rowBase + j * 64 + rowS) * strideK2 + kA;
        __builtin_amdgcn_global_load_lds((const AS1 void*)src,
                                         (AS3 void*)(lb + j * 8192 + tid * 16), 16, 0, 0);
      }
    }
    {
      char* lb = (char*)&Bs[0][0];
      #pragma unroll
      for (int j = 0; j < 2; j++){
        const ushort* src = Bg + (size_t)(colBase + j * 64 + rowS) * strideK2 + kA;
        __builtin_amdgcn_global_load_lds((const AS1 void*)src,
                                         (AS3 void*)(lb + j * 8192 + tid * 16), 16, 0, 0);
      }
    }
  };

  bf16x8 ah[4], al[4], bh[4], bl[4];
  auto readAll = [&](){
    #pragma unroll
    for (int n = 0; n < 4; n++){
      bh[n] = *(const bf16x8*)&Bs[wc * 64 + n * 16 + lr][lk ^ swzR];
      bl[n] = *(const bf16x8*)&Bs[wc * 64 + n * 16 + lr][(32 + lk) ^ swzR];
    }
    #pragma unroll
    for (int m = 0; m < 4; m++){
      ah[m] = *(const bf16x8*)&As[wrow * 64 + m * 16 + lr][lk ^ swzR];
      al[m] = *(const bf16x8*)&As[wrow * 64 + m * 16 + lr][(32 + lk) ^ swzR];
    }
  };

  f32x4 acc[4][4];
  #pragma unroll
  for (int m = 0; m < 4; m++)
    #pragma unroll
    for (int n = 0; n < 4; n++)
      acc[m][n] = (f32x4){0.f, 0.f, 0.f, 0.f};

  // prologue
  stage(0);

  for (int t = 0; t < KB; ++t){
    asm volatile("s_waitcnt vmcnt(0)" ::: "memory");  // tile t landed
    SCHED0; SBAR; SCHED0;                             // visible to all
    readAll();
    asm volatile("s_waitcnt lgkmcnt(0)" ::: "memory"); SCHED0;
    SBAR; SCHED0;                                     // buffer free blockwide
    stage(t + 1); SCHED0;                             // DMA rides under MFMA
    __builtin_amdgcn_s_setprio(1);
    #pragma unroll
    for (int m = 0; m < 4; m++)
      #pragma unroll
      for (int n = 0; n < 4; n++){
        f32x4 c = acc[m][n];
        c = __builtin_amdgcn_mfma_f32_16x16x32_bf16(al[m], bh[n], c, 0, 0, 0);
        c = __builtin_amdgcn_mfma_f32_16x16x32_bf16(ah[m], bh[n], c, 0, 0, 0);
        c = __builtin_amdgcn_mfma_f32_16x16x32_bf16(ah[m], bl[n], c, 0, 0, 0);
        acc[m][n] = c;
      }
    __builtin_amdgcn_s_setprio(0);
    SCHED0;
  }
  asm volatile("s_waitcnt vmcnt(0)" ::: "memory");    // drain dead last stage

  // ---- epilogue ----
  // acc[m][n]: row = rowBase + wrow*64 + m*16 + (lane>>4)*4 + r
  //            col = colBase + wc*64 + n*16 + lr
  if (sl.mode == 2){
    // fused final expert layer, partial over this 128-col half
    __syncthreads();
    #pragma unroll
    for (int m = 0; m < 4; m++){
      float p4[4] = {0.f, 0.f, 0.f, 0.f};
      #pragma unroll
      for (int n = 0; n < 4; n++){
        int col = colBase + wc * 64 + n * 16 + lr;
        float bv = sl.bias[col];
        float wv = sl.w3[col];
        #pragma unroll
        for (int r = 0; r < 4; r++)
          p4[r] += elu_f(acc[m][n][r] + bv) * wv;
      }
      #pragma unroll
      for (int r = 0; r < 4; r++){
        #pragma unroll
        for (int s = 8; s > 0; s >>= 1) p4[r] += __shfl_xor(p4[r], s, 64);
      }
      if ((lane & 15) == 0){
        int hig = lane >> 4;
        int rowoff = wrow * 64 + m * 16 + hig * 4;
        #pragma unroll
        for (int r = 0; r < 4; r++)
          red[wc][rowoff + r] = p4[r];
      }
    }
    __syncthreads();
    if (tid < 256){
      float s2 = red[0][tid] + red[1][tid];
      sl.ret[((size_t)bx * 8192 + rowBase + tid) * 8 + sl.eidx] = s2;  // bias in combine
    }
    return;
  }

  const int N = sl.N;
  #pragma unroll
  for (int m = 0; m < 4; m++){
    int row0 = rowBase + wrow * 64 + m * 16 + ((lane >> 4) << 2);
    #pragma unroll
    for (int n = 0; n < 4; n++){
      int col = colBase + wc * 64 + n * 16 + lr;
      float bv = sl.bias[col];
      float v0 = elu_f(acc[m][n][0] + bv);
      float v1 = elu_f(acc[m][n][1] + bv);
      float v2 = elu_f(acc[m][n][2] + bv);
      float v3 = elu_f(acc[m][n][3] + bv);
      if (sl.mode == 0){
        unsigned ph01, ph23, pl01, pl23;
        asm("v_cvt_pk_bf16_f32 %0, %1, %2" : "=v"(ph01) : "v"(v0), "v"(v1));
        asm("v_cvt_pk_bf16_f32 %0, %1, %2" : "=v"(ph23) : "v"(v2), "v"(v3));
        union { unsigned u; float f; } c0, c1, c2, c3;
        c0.u = ph01 << 16; c1.u = ph01 & 0xffff0000u;
        c2.u = ph23 << 16; c3.u = ph23 & 0xffff0000u;
        asm("v_cvt_pk_bf16_f32 %0, %1, %2" : "=v"(pl01) : "v"(v0 - c0.f), "v"(v1 - c1.f));
        asm("v_cvt_pk_bf16_f32 %0, %1, %2" : "=v"(pl23) : "v"(v2 - c2.f), "v"(v3 - c3.f));
        ushort* C = (ushort*)sl.C;
        size_t s2n = (size_t)(2 * N);
        size_t r0b = (size_t)row0 * s2n + col;
        C[r0b]            = (ushort)ph01;
        C[r0b + s2n]      = (ushort)(ph01 >> 16);
        C[r0b + 2 * s2n]  = (ushort)ph23;
        C[r0b + 3 * s2n]  = (ushort)(ph23 >> 16);
        size_t r0l = r0b + N;
        C[r0l]            = (ushort)pl01;
        C[r0l + s2n]      = (ushort)(pl01 >> 16);
        C[r0l + 2 * s2n]  = (ushort)pl23;
        C[r0l + 3 * s2n]  = (ushort)(pl23 >> 16);
      } else {
        float* C = (float*)sl.C;
        size_t r0b = (size_t)row0 * N + col;
        C[r0b]         = v0;
        C[r0b + N]     = v1;
        C[r0b + 2 * N] = v2;
        C[r0b + 3 * N] = v3;
      }
    }
  }
}

// ---- gate final layer + softmax ----
__global__ void gate3_softmax(const float* __restrict__ g2, const float* __restrict__ gw3,
                              const float* __restrict__ gb3, float* __restrict__ wts){
  int row = blockIdx.x * 4 + (threadIdx.x >> 6);
  int lane = threadIdx.x & 63;
  const float* g = g2 + (size_t)row * 256;
  float p[8];
  #pragma unroll
  for (int j = 0; j < 8; j++) p[j] = 0.f;
  for (int k = lane; k < 256; k += 64){
    float x = g[k];
    #pragma unroll
    for (int j = 0; j < 8; j++) p[j] += x * gw3[k * 8 + j];
  }
  #pragma unroll
  for (int j = 0; j < 8; j++){
    #pragma unroll
    for (int s = 32; s > 0; s >>= 1) p[j] += __shfl_xor(p[j], s, 64);
  }
  float mx = -1e30f;
  #pragma unroll
  for (int j = 0; j < 8; j++){ p[j] += gb3[j]; mx = fmaxf(mx, p[j]); }
  float sum = 0.f;
  #pragma unroll
  for (int j = 0; j < 8; j++){ p[j] = expf(p[j] - mx); sum += p[j]; }
  float inv = 1.f / sum;
  #pragma unroll
  for (int j = 0; j < 8; j++)
    if (lane == j) wts[(size_t)row * 8 + j] = p[j] * inv;
}

// ---- final combine: ret2 holds two col-half partials; add eb3 here ----
__global__ void combine(const float* __restrict__ wts, const float* __restrict__ ret2,
                        const float* __restrict__ eb3, float* __restrict__ out){
  int i = blockIdx.x * blockDim.x + threadIdx.x;
  if (i >= 8192) return;
  float s = 0.f;
  #pragma unroll
  for (int j = 0; j < 8; j++){
    float r = ret2[(size_t)i * 8 + j] + ret2[65536 + (size_t)i * 8 + j] + eb3[j];
    s += wts[(size_t)i * 8 + j] * r;
  }
  out[i] = s;
}

extern "C" void kernel_launch(void* const* d_in, const int* in_sizes, int n_in,
                              void* d_out, int out_size, void* d_ws, size_t ws_size,
                              hipStream_t stream){
  const float* obs  = (const float*)d_in[0];
  const float* code = (const float*)d_in[1];
  const float* ew0  = (const float*)d_in[2];
  const float* eb0  = (const float*)d_in[3];
  const float* ew1  = (const float*)d_in[4];
  const float* eb1  = (const float*)d_in[5];
  const float* ew2  = (const float*)d_in[6];
  const float* eb2  = (const float*)d_in[7];
  const float* ew3  = (const float*)d_in[8];
  const float* eb3  = (const float*)d_in[9];
  const float* gw0  = (const float*)d_in[10];
  const float* gb0  = (const float*)d_in[11];
  const float* gw1  = (const float*)d_in[12];
  const float* gb1  = (const float*)d_in[13];
  const float* gw2  = (const float*)d_in[14];
  const float* gb2  = (const float*)d_in[15];
  const float* gw3  = (const float*)d_in[16];
  const float* gb3  = (const float*)d_in[17];
  (void)in_sizes; (void)n_in; (void)out_size;

  char* ws = (char*)d_ws;
  size_t off = 0;
  auto alloc = [&](size_t bytes) -> void* {
    void* p = ws + off;
    off += (bytes + 255) & ~(size_t)255;
    return p;
  };
  ushort* A_obs  = (ushort*)alloc(8192ull * 1024 * 2);
  ushort* A_code = (ushort*)alloc(8192ull * 128 * 2);
  ushort* B_ew0  = (ushort*)alloc(8ull * 1024 * 1024 * 2);
  ushort* B_ew1  = (ushort*)alloc(8ull * 512 * 2048 * 2);
  ushort* B_ew2  = (ushort*)alloc(8ull * 256 * 1024 * 2);
  ushort* B_gw0  = (ushort*)alloc(1024ull * 128 * 2);
  ushort* B_gw1  = (ushort*)alloc(512ull * 2048 * 2);
  ushort* B_gw2  = (ushort*)alloc(256ull * 1024 * 2);
  float*  wts    = (float*)alloc(8192ull * 8 * 4);
  float*  ret2   = (float*)alloc(2ull * 8192 * 8 * 4);   // two col-half partials
  const size_t fixed = off;

  const size_t sl0b = 8192ull * 2048 * 2;   // h0 split bf16 (32MiB)
  const size_t sl1b = 8192ull * 1024 * 2;   // h1 split bf16 (16MiB)
  const size_t pairB = sl0b + sl1b;

  int G = 0;
  {
    const int cand[5] = {8, 4, 3, 2, 1};
    for (int ci = 0; ci < 5; ci++)
      if (fixed + (size_t)(cand[ci] + 1) * pairB <= ws_size){ G = cand[ci]; break; }
  }
  const bool gateFirst = (G == 0);
  const int ns = gateFirst ? 1 : (G + 1);
  ushort* h0buf = (ushort*)alloc((size_t)ns * sl0b);
  ushort* h1buf = (ushort*)alloc((size_t)ns * sl1b);
  const size_t sl0e = 8192ull * 2048;
  const size_t sl1e = 8192ull * 1024;
  const int gsl = ns - 1;
  ushort* h0g = h0buf + (size_t)gsl * sl0e;
  ushort* h1g = h1buf + (size_t)gsl * sl1e;
  float*  h2g = (float*)h0g;                 // alias: h0g dead after gate L1

  // prep (2 dispatches)
  {
    AJob j0 = {obs,  A_obs,  8192 * 512, 512};
    AJob j1 = {code, A_code, 8192 * 64,  64};
    int t0 = 8192 * 512;
    prep_act_all<<<dim3((t0 + j1.total + 255) / 256), 256, 0, stream>>>(j0, j1, t0);

    WJobs wj; wj.njobs = 6;
    int bs = 0;
    auto addW = [&](int i, const float* W, ushort* Bt, int K, int N, int E){
      wj.j[i] = {W, Bt, K, N, N / 32, K / 32, bs};
      bs += E * (N / 32) * (K / 32);
    };
    addW(0, ew0, B_ew0, 512, 1024, 8);
    addW(1, ew1, B_ew1, 1024, 512, 8);
    addW(2, ew2, B_ew2, 512, 256, 8);
    addW(3, gw0, B_gw0, 64, 1024, 1);
    addW(4, gw1, B_gw1, 1024, 512, 1);
    addW(5, gw2, B_gw2, 512, 256, 1);
    prep_w_all<<<dim3(bs), dim3(32, 8), 0, stream>>>(wj);
  }

  // per-slice block counts at 256x128 tiles (gy = 8192/256 = 32)
  const int NB0 = 8 * 32;    // L0: N=1024 -> gx=8 -> 256
  const int NB1 = 4 * 32;    // L1: N=512  -> gx=4 -> 128
  const int NB2 = 2 * 32;    // L2: N=256  -> gx=2 -> 64

  auto runGroup = [&](int e0, int cnt, bool withGate){
    SliceArr sa; int nb;
    // L0
    nb = 0; sa.nz = cnt + (withGate ? 1 : 0);
    for (int i = 0; i < cnt; i++){ int e = e0 + i;
      sa.s[i] = {A_obs, B_ew0 + (size_t)e * 1024 * 1024, eb0 + e * 1024,
                 h0buf + (size_t)i * sl0e, nullptr, nullptr, nullptr,
                 1024, 512, 3, 0, nb, 0};
      nb += NB0;
    }
    if (withGate){
      sa.s[cnt] = {A_code, B_gw0, gb0, h0g, nullptr, nullptr, nullptr,
                   1024, 64, 3, 0, nb, 0};
      nb += NB0;
    }
    for (int i = sa.nz; i < 9; i++) sa.s[i] = sa.s[0];
    gemm8p<<<dim3(nb), 512, 0, stream>>>(sa);
    // L1
    nb = 0;
    for (int i = 0; i < cnt; i++){ int e = e0 + i;
      sa.s[i] = {h0buf + (size_t)i * sl0e, B_ew1 + (size_t)e * 512 * 2048, eb1 + e * 512,
                 h1buf + (size_t)i * sl1e, nullptr, nullptr, nullptr,
                 512, 1024, 2, 0, nb, 0};
      nb += NB1;
    }
    if (withGate){
      sa.s[cnt] = {h0g, B_gw1, gb1, h1g, nullptr, nullptr, nullptr,
                   512, 1024, 2, 0, nb, 0};
      nb += NB1;
    }
    gemm8p<<<dim3(nb), 512, 0, stream>>>(sa);
    // L2: experts fused-returns partials (mode 2); gate f32 h2 (mode 1)
    nb = 0;
    for (int i = 0; i < cnt; i++){ int e = e0 + i;
      sa.s[i] = {h1buf + (size_t)i * sl1e, B_ew2 + (size_t)e * 256 * 1024, eb2 + e * 256,
                 nullptr, ew3 + (size_t)e * 256, eb3 + e, ret2,
                 256, 512, 1, 2, nb, e};
      nb += NB2;
    }
    if (withGate){
      sa.s[cnt] = {h1g, B_gw2, gb2, h2g, nullptr, nullptr, nullptr,
                   256, 512, 1, 1, nb, 0};
      nb += NB2;
    }
    gemm8p<<<dim3(nb), 512, 0, stream>>>(sa);
    if (withGate)
      gate3_softmax<<<dim3(2048), 256, 0, stream>>>(h2g, gw3, gb3, wts);
  };

  if (gateFirst){
    SliceArr sa; sa.nz = 1;
    sa.s[0] = {A_code, B_gw0, gb0, h0g, nullptr, nullptr, nullptr, 1024, 64, 3, 0, 0, 0};
    for (int i = 1; i < 9; i++) sa.s[i] = sa.s[0];
    gemm8p<<<dim3(NB0), 512, 0, stream>>>(sa);
    sa.s[0] = {h0g, B_gw1, gb1, h1g, nullptr, nullptr, nullptr, 512, 1024, 2, 0, 0, 0};
    gemm8p<<<dim3(NB1), 512, 0, stream>>>(sa);
    sa.s[0] = {h1g, B_gw2, gb2, h2g, nullptr, nullptr, nullptr, 256, 512, 1, 1, 0, 0};
    gemm8p<<<dim3(NB2), 512, 0, stream>>>(sa);
    gate3_softmax<<<dim3(2048), 256, 0, stream>>>(h2g, gw3, gb3, wts);
    for (int e = 0; e < 8; e++) runGroup(e, 1, false);
  } else {
    bool first = true;
    for (int e0 = 0; e0 < 8; ){
      int cnt = (8 - e0 < G) ? (8 - e0) : G;
      runGroup(e0, cnt, first);
      first = false;
      e0 += cnt;
    }
  }

  combine<<<dim3(8192 / 256), 256, 0, stream>>>(wts, ret2, eb3, (float*)d_out);
}

// Round 13
// 515.975 us; speedup vs baseline: 1.2927x; 1.2927x over previous
//
#include <hip/hip_runtime.h>
#include <hip/hip_bf16.h>
#include <math.h>

// B=8192, D=512, V=64, E=8, hidden (1024,512,256)
// Round 13: R12 (f16 split-A x single-f16 B, 2 MFMAs per 32-k step, 24KB
// staged/step, R10 geometry) with the cvt_pkrtz return-type compile fix.

typedef _Float16 f16x8 __attribute__((ext_vector_type(8)));
typedef float f32x4 __attribute__((ext_vector_type(4)));

#define AS1 __attribute__((address_space(1)))
#define AS3 __attribute__((address_space(3)))
#define SCHED0 __builtin_amdgcn_sched_barrier(0)
#define SBAR __builtin_amdgcn_s_barrier()

__device__ __forceinline__ ushort h2u(_Float16 h){
  union { _Float16 h; ushort u; } v; v.h = h; return v.u;
}
__device__ __forceinline__ ushort h2u(__fp16 h){
  union { __fp16 h; ushort u; } v; v.h = h; return v.u;
}
__device__ __forceinline__ float elu_f(float x){
  return x > 0.f ? x : __expf(x) - 1.f;
}

// ---- unified prep: activations f32 [rows][K] -> [rows][2K] f16 hi|lo ----
struct AJob { const float* X; ushort* A; int total, K; };
__global__ void prep_act_all(AJob j0, AJob j1, int t0){
  int i = blockIdx.x * 256 + threadIdx.x;
  AJob J; int idx;
  if (i < t0){ J = j0; idx = i; }
  else { J = j1; idx = i - t0; if (idx >= J.total) return; }
  int row = idx / J.K, k = idx - row * J.K;
  float x = J.X[idx];
  _Float16 hi = (_Float16)x;                  // RN
  _Float16 lo = (_Float16)(x - (float)hi);
  size_t base = (size_t)row * (size_t)(2 * J.K);
  J.A[base + k] = h2u(hi);
  J.A[base + J.K + k] = h2u(lo);
}

// ---- unified prep: weights f32 [E][K][N] -> [E][N][K] single f16 ----
struct WJob { const float* W; ushort* Bt; int K, N, nb, nk, blkStart; };
struct WJobs { WJob j[6]; int njobs; };
__global__ void prep_w_all(WJobs jobs){
  __shared__ float tile[32][33];
  int b = blockIdx.x;
  int ji = 0;
  while (ji + 1 < jobs.njobs && b >= jobs.j[ji + 1].blkStart) ji++;
  WJob J = jobs.j[ji];
  int rem = b - J.blkStart;
  int x = rem % J.nb; rem /= J.nb;
  int y = rem % J.nk; int e = rem / J.nk;
  const float* w = J.W + (size_t)e * J.K * J.N;
  ushort* bt = J.Bt + (size_t)e * J.N * J.K;
  int n0 = x * 32, k0 = y * 32;
  for (int i = threadIdx.y; i < 32; i += 8)
    tile[i][threadIdx.x] = w[(size_t)(k0 + i) * J.N + n0 + threadIdx.x];
  __syncthreads();
  for (int jj = threadIdx.y; jj < 32; jj += 8){
    float v = tile[threadIdx.x][jj];
    bt[(size_t)(n0 + jj) * J.K + k0 + threadIdx.x] = h2u((_Float16)v);
  }
}

// ---- descriptor-batched 128x128 GEMM, f16 2-product, 32-k steps ----
// mode 0: C = split f16 [M][2N]; mode 1: C = f32 [M][N];
// mode 2: no C — ret[bx][row][eidx] = partial sum_col elu(acc+bias)*w3
struct Slice {
  const ushort* A; const ushort* Bt; const float* bias; void* C;
  const float* w3; const float* rbp; float* ret;
  int N, K, log2gx, mode, blkStart, eidx;
};
struct SliceArr { Slice s[9]; int nz; };

__global__ __launch_bounds__(256, 3) void gemm8p(SliceArr args){
  // A tile [128][64]: cols 0..31 = hi k0..31, cols 32..63 = lo k0..31 (16KB)
  // B tile [128][32]: single f16 k0..31 (8KB)
  __shared__ __align__(16) ushort As[128][64];
  __shared__ __align__(16) ushort Bs[128][32];
  __shared__ float red[2][128];

  // XCD-chunked bijective swizzle (grids here are multiples of 8)
  const int nwg  = gridDim.x;
  const int orig = blockIdx.x;
  const int wg   = (orig & 7) * (nwg >> 3) + (orig >> 3);

  int z = 0;
  while (z + 1 < args.nz && wg >= args.s[z + 1].blkStart) z++;
  const Slice sl = args.s[z];
  const int rem = wg - sl.blkStart;
  const int gxm = (1 << sl.log2gx) - 1;
  const int bx  = rem & gxm;
  const int by  = rem >> sl.log2gx;

  const ushort* __restrict__ Ag = sl.A;
  const ushort* __restrict__ Bg = sl.Bt;
  const int K = sl.K;

  const int tid  = threadIdx.x;
  const int lane = tid & 63;
  const int wave = tid >> 6;                    // 0..3
  const int wr = wave >> 1;                     // 0..1 : rows wr*64..+63
  const int wc = wave & 1;                      // 0..1 : cols wc*64..+63
  const int rowBase = by * 128;
  const int colBase = bx * 128;
  const int KB = K >> 5;                        // 32-k steps
  const int lr = lane & 15;
  const int lk = (lane >> 4) << 3;
  const int swzR = (lr & 7) << 3;
  const size_t strideK2 = (size_t)(2 * K);      // A stride (hi|lo)

  const int rowS = tid >> 3;                    // 0..31 (A staging)
  const int swzS = ((tid >> 3) & 7) << 3;
  const int colS = ((tid & 7) << 3) ^ swzS;     // 0..63 (kind in bit 5)

  // stage A (16KB, 4 instrs) + B (8KB, 2 instrs) of 32-k step kt
  auto stage = [&](int kt){
    int tt = (kt < KB) ? kt : (KB - 1);         // clamp: dead-but-safe
    int kA = ((colS & 32) ? K : 0) + (tt << 5) + (colS & 31);
    {
      char* lb = (char*)&As[0][0];
      #pragma unroll
      for (int j = 0; j < 4; j++){
        const ushort* src = Ag + (size_t)(rowBase + j * 32 + rowS) * strideK2 + kA;
        __builtin_amdgcn_global_load_lds((const AS1 void*)src,
                                         (AS3 void*)(lb + j * 4096 + tid * 16), 16, 0, 0);
      }
    }
    {
      char* lb = (char*)&Bs[0][0];
      int kB = (tt << 5) + ((tid & 3) << 3);
      #pragma unroll
      for (int j = 0; j < 2; j++){
        int row = j * 64 + (tid >> 2);
        const ushort* src = Bg + (size_t)(colBase + row) * K + kB;
        __builtin_amdgcn_global_load_lds((const AS1 void*)src,
                                         (AS3 void*)(lb + j * 4096 + tid * 16), 16, 0, 0);
      }
    }
  };

  f16x8 ah[4], al[4], b[4];
  auto readAll = [&](){
    #pragma unroll
    for (int n = 0; n < 4; n++)
      b[n] = *(const f16x8*)&Bs[wc * 64 + n * 16 + lr][lk];
    #pragma unroll
    for (int m = 0; m < 4; m++){
      ah[m] = *(const f16x8*)&As[wr * 64 + m * 16 + lr][lk ^ swzR];
      al[m] = *(const f16x8*)&As[wr * 64 + m * 16 + lr][(32 + lk) ^ swzR];
    }
  };

  f32x4 acc[4][4];
  #pragma unroll
  for (int m = 0; m < 4; m++)
    #pragma unroll
    for (int n = 0; n < 4; n++)
      acc[m][n] = (f32x4){0.f, 0.f, 0.f, 0.f};

  // prologue
  stage(0);

  for (int t = 0; t < KB; ++t){
    asm volatile("s_waitcnt vmcnt(0)" ::: "memory");  // tile t landed
    SCHED0; SBAR; SCHED0;
    readAll();
    asm volatile("s_waitcnt lgkmcnt(0)" ::: "memory"); SCHED0;
    SBAR; SCHED0;                                     // buffer free blockwide
    stage(t + 1); SCHED0;                             // DMA rides under MFMA
    __builtin_amdgcn_s_setprio(1);
    #pragma unroll
    for (int m = 0; m < 4; m++)
      #pragma unroll
      for (int n = 0; n < 4; n++){
        f32x4 c = acc[m][n];
        c = __builtin_amdgcn_mfma_f32_16x16x32_f16(al[m], b[n], c, 0, 0, 0);
        c = __builtin_amdgcn_mfma_f32_16x16x32_f16(ah[m], b[n], c, 0, 0, 0);
        acc[m][n] = c;
      }
    __builtin_amdgcn_s_setprio(0);
    SCHED0;
  }
  asm volatile("s_waitcnt vmcnt(0)" ::: "memory");    // drain dead last stage

  // ---- epilogue ----
  // acc[m][n]: row = rowBase + wr*64 + m*16 + (lane>>4)*4 + r
  //            col = colBase + wc*64 + n*16 + lr
  if (sl.mode == 2){
    __syncthreads();
    #pragma unroll
    for (int m = 0; m < 4; m++){
      float p4[4] = {0.f, 0.f, 0.f, 0.f};
      #pragma unroll
      for (int n = 0; n < 4; n++){
        int col = colBase + wc * 64 + n * 16 + lr;
        float bv = sl.bias[col];
        float wv = sl.w3[col];
        #pragma unroll
        for (int r = 0; r < 4; r++)
          p4[r] += elu_f(acc[m][n][r] + bv) * wv;
      }
      #pragma unroll
      for (int r = 0; r < 4; r++){
        #pragma unroll
        for (int s = 8; s > 0; s >>= 1) p4[r] += __shfl_xor(p4[r], s, 64);
      }
      if ((lane & 15) == 0){
        int hig = lane >> 4;
        int rowoff = wr * 64 + m * 16 + hig * 4;
        #pragma unroll
        for (int r = 0; r < 4; r++)
          red[wc][rowoff + r] = p4[r];
      }
    }
    __syncthreads();
    if (tid < 128){
      float s2 = red[0][tid] + red[1][tid];
      sl.ret[((size_t)bx * 8192 + rowBase + tid) * 8 + sl.eidx] = s2;  // bias in combine
    }
    return;
  }

  const int N = sl.N;
  #pragma unroll
  for (int m = 0; m < 4; m++){
    int row0 = rowBase + wr * 64 + m * 16 + ((lane >> 4) << 2);
    #pragma unroll
    for (int n = 0; n < 4; n++){
      int col = colBase + wc * 64 + n * 16 + lr;
      float bv = sl.bias[col];
      float v0 = elu_f(acc[m][n][0] + bv);
      float v1 = elu_f(acc[m][n][1] + bv);
      float v2 = elu_f(acc[m][n][2] + bv);
      float v3 = elu_f(acc[m][n][3] + bv);
      if (sl.mode == 0){
        auto hp01 = __builtin_amdgcn_cvt_pkrtz(v0, v1);
        auto hp23 = __builtin_amdgcn_cvt_pkrtz(v2, v3);
        auto lp01 = __builtin_amdgcn_cvt_pkrtz(v0 - (float)hp01[0], v1 - (float)hp01[1]);
        auto lp23 = __builtin_amdgcn_cvt_pkrtz(v2 - (float)hp23[0], v3 - (float)hp23[1]);
        ushort* C = (ushort*)sl.C;
        size_t s2n = (size_t)(2 * N);
        size_t r0b = (size_t)row0 * s2n + col;
        C[r0b]            = h2u(hp01[0]);
        C[r0b + s2n]      = h2u(hp01[1]);
        C[r0b + 2 * s2n]  = h2u(hp23[0]);
        C[r0b + 3 * s2n]  = h2u(hp23[1]);
        size_t r0l = r0b + N;
        C[r0l]            = h2u(lp01[0]);
        C[r0l + s2n]      = h2u(lp01[1]);
        C[r0l + 2 * s2n]  = h2u(lp23[0]);
        C[r0l + 3 * s2n]  = h2u(lp23[1]);
      } else {
        float* C = (float*)sl.C;
        size_t r0b = (size_t)row0 * N + col;
        C[r0b]         = v0;
        C[r0b + N]     = v1;
        C[r0b + 2 * N] = v2;
        C[r0b + 3 * N] = v3;
      }
    }
  }
}

// ---- gate final layer + softmax ----
__global__ void gate3_softmax(const float* __restrict__ g2, const float* __restrict__ gw3,
                              const float* __restrict__ gb3, float* __restrict__ wts){
  int row = blockIdx.x * 4 + (threadIdx.x >> 6);
  int lane = threadIdx.x & 63;
  const float* g = g2 + (size_t)row * 256;
  float p[8];
  #pragma unroll
  for (int j = 0; j < 8; j++) p[j] = 0.f;
  for (int k = lane; k < 256; k += 64){
    float x = g[k];
    #pragma unroll
    for (int j = 0; j < 8; j++) p[j] += x * gw3[k * 8 + j];
  }
  #pragma unroll
  for (int j = 0; j < 8; j++){
    #pragma unroll
    for (int s = 32; s > 0; s >>= 1) p[j] += __shfl_xor(p[j], s, 64);
  }
  float mx = -1e30f;
  #pragma unroll
  for (int j = 0; j < 8; j++){ p[j] += gb3[j]; mx = fmaxf(mx, p[j]); }
  float sum = 0.f;
  #pragma unroll
  for (int j = 0; j < 8; j++){ p[j] = expf(p[j] - mx); sum += p[j]; }
  float inv = 1.f / sum;
  #pragma unroll
  for (int j = 0; j < 8; j++)
    if (lane == j) wts[(size_t)row * 8 + j] = p[j] * inv;
}

// ---- final combine: ret2 holds two col-half partials; add eb3 here ----
__global__ void combine(const float* __restrict__ wts, const float* __restrict__ ret2,
                        const float* __restrict__ eb3, float* __restrict__ out){
  int i = blockIdx.x * blockDim.x + threadIdx.x;
  if (i >= 8192) return;
  float s = 0.f;
  #pragma unroll
  for (int j = 0; j < 8; j++){
    float r = ret2[(size_t)i * 8 + j] + ret2[65536 + (size_t)i * 8 + j] + eb3[j];
    s += wts[(size_t)i * 8 + j] * r;
  }
  out[i] = s;
}

extern "C" void kernel_launch(void* const* d_in, const int* in_sizes, int n_in,
                              void* d_out, int out_size, void* d_ws, size_t ws_size,
                              hipStream_t stream){
  const float* obs  = (const float*)d_in[0];
  const float* code = (const float*)d_in[1];
  const float* ew0  = (const float*)d_in[2];
  const float* eb0  = (const float*)d_in[3];
  const float* ew1  = (const float*)d_in[4];
  const float* eb1  = (const float*)d_in[5];
  const float* ew2  = (const float*)d_in[6];
  const float* eb2  = (const float*)d_in[7];
  const float* ew3  = (const float*)d_in[8];
  const float* eb3  = (const float*)d_in[9];
  const float* gw0  = (const float*)d_in[10];
  const float* gb0  = (const float*)d_in[11];
  const float* gw1  = (const float*)d_in[12];
  const float* gb1  = (const float*)d_in[13];
  const float* gw2  = (const float*)d_in[14];
  const float* gb2  = (const float*)d_in[15];
  const float* gw3  = (const float*)d_in[16];
  const float* gb3  = (const float*)d_in[17];
  (void)in_sizes; (void)n_in; (void)out_size;

  char* ws = (char*)d_ws;
  size_t off = 0;
  auto alloc = [&](size_t bytes) -> void* {
    void* p = ws + off;
    off += (bytes + 255) & ~(size_t)255;
    return p;
  };
  ushort* A_obs  = (ushort*)alloc(8192ull * 1024 * 2);     // [8192][2*512] f16
  ushort* A_code = (ushort*)alloc(8192ull * 128 * 2);      // [8192][2*64] f16
  ushort* B_ew0  = (ushort*)alloc(8ull * 1024 * 512 * 2);  // [8][1024][512] f16
  ushort* B_ew1  = (ushort*)alloc(8ull * 512 * 1024 * 2);
  ushort* B_ew2  = (ushort*)alloc(8ull * 256 * 512 * 2);
  ushort* B_gw0  = (ushort*)alloc(1024ull * 64 * 2);
  ushort* B_gw1  = (ushort*)alloc(512ull * 1024 * 2);
  ushort* B_gw2  = (ushort*)alloc(256ull * 512 * 2);
  float*  wts    = (float*)alloc(8192ull * 8 * 4);
  float*  ret2   = (float*)alloc(2ull * 8192 * 8 * 4);
  const size_t fixed = off;

  const size_t sl0b = 8192ull * 2048 * 2;   // h0 split f16 (32MiB)
  const size_t sl1b = 8192ull * 1024 * 2;   // h1 split f16 (16MiB)
  const size_t pairB = sl0b + sl1b;

  int G = 0;
  {
    const int cand[5] = {8, 4, 3, 2, 1};
    for (int ci = 0; ci < 5; ci++)
      if (fixed + (size_t)(cand[ci] + 1) * pairB <= ws_size){ G = cand[ci]; break; }
  }
  const bool gateFirst = (G == 0);
  const int ns = gateFirst ? 1 : (G + 1);
  ushort* h0buf = (ushort*)alloc((size_t)ns * sl0b);
  ushort* h1buf = (ushort*)alloc((size_t)ns * sl1b);
  const size_t sl0e = 8192ull * 2048;
  const size_t sl1e = 8192ull * 1024;
  const int gsl = ns - 1;
  ushort* h0g = h0buf + (size_t)gsl * sl0e;
  ushort* h1g = h1buf + (size_t)gsl * sl1e;
  float*  h2g = (float*)h0g;                 // alias: h0g dead after gate L1

  // prep (2 dispatches)
  {
    AJob j0 = {obs,  A_obs,  8192 * 512, 512};
    AJob j1 = {code, A_code, 8192 * 64,  64};
    int t0 = 8192 * 512;
    prep_act_all<<<dim3((t0 + j1.total + 255) / 256), 256, 0, stream>>>(j0, j1, t0);

    WJobs wj; wj.njobs = 6;
    int bs = 0;
    auto addW = [&](int i, const float* W, ushort* Bt, int K, int N, int E){
      wj.j[i] = {W, Bt, K, N, N / 32, K / 32, bs};
      bs += E * (N / 32) * (K / 32);
    };
    addW(0, ew0, B_ew0, 512, 1024, 8);
    addW(1, ew1, B_ew1, 1024, 512, 8);
    addW(2, ew2, B_ew2, 512, 256, 8);
    addW(3, gw0, B_gw0, 64, 1024, 1);
    addW(4, gw1, B_gw1, 1024, 512, 1);
    addW(5, gw2, B_gw2, 512, 256, 1);
    prep_w_all<<<dim3(bs), dim3(32, 8), 0, stream>>>(wj);
  }

  // per-slice block counts at 128x128 tiles (gy = 64)
  const int NB0 = 8 * 64;    // L0: N=1024 -> 512
  const int NB1 = 4 * 64;    // L1: N=512  -> 256
  const int NB2 = 2 * 64;    // L2: N=256  -> 128

  auto runGroup = [&](int e0, int cnt, bool withGate){
    SliceArr sa; int nb;
    // L0
    nb = 0; sa.nz = cnt + (withGate ? 1 : 0);
    for (int i = 0; i < cnt; i++){ int e = e0 + i;
      sa.s[i] = {A_obs, B_ew0 + (size_t)e * 1024 * 512, eb0 + e * 1024,
                 h0buf + (size_t)i * sl0e, nullptr, nullptr, nullptr,
                 1024, 512, 3, 0, nb, 0};
      nb += NB0;
    }
    if (withGate){
      sa.s[cnt] = {A_code, B_gw0, gb0, h0g, nullptr, nullptr, nullptr,
                   1024, 64, 3, 0, nb, 0};
      nb += NB0;
    }
    for (int i = sa.nz; i < 9; i++) sa.s[i] = sa.s[0];
    gemm8p<<<dim3(nb), 256, 0, stream>>>(sa);
    // L1
    nb = 0;
    for (int i = 0; i < cnt; i++){ int e = e0 + i;
      sa.s[i] = {h0buf + (size_t)i * sl0e, B_ew1 + (size_t)e * 512 * 1024, eb1 + e * 512,
                 h1buf + (size_t)i * sl1e, nullptr, nullptr, nullptr,
                 512, 1024, 2, 0, nb, 0};
      nb += NB1;
    }
    if (withGate){
      sa.s[cnt] = {h0g, B_gw1, gb1, h1g, nullptr, nullptr, nullptr,
                   512, 1024, 2, 0, nb, 0};
      nb += NB1;
    }
    gemm8p<<<dim3(nb), 256, 0, stream>>>(sa);
    // L2: experts fused-returns partials (mode 2); gate f32 h2 (mode 1)
    nb = 0;
    for (int i = 0; i < cnt; i++){ int e = e0 + i;
      sa.s[i] = {h1buf + (size_t)i * sl1e, B_ew2 + (size_t)e * 256 * 512, eb2 + e * 256,
                 nullptr, ew3 + (size_t)e * 256, eb3 + e, ret2,
                 256, 512, 1, 2, nb, e};
      nb += NB2;
    }
    if (withGate){
      sa.s[cnt] = {h1g, B_gw2, gb2, h2g, nullptr, nullptr, nullptr,
                   256, 512, 1, 1, nb, 0};
      nb += NB2;
    }
    gemm8p<<<dim3(nb), 256, 0, stream>>>(sa);
    if (withGate)
      gate3_softmax<<<dim3(2048), 256, 0, stream>>>(h2g, gw3, gb3, wts);
  };

  if (gateFirst){
    SliceArr sa; sa.nz = 1;
    sa.s[0] = {A_code, B_gw0, gb0, h0g, nullptr, nullptr, nullptr, 1024, 64, 3, 0, 0, 0};
    for (int i = 1; i < 9; i++) sa.s[i] = sa.s[0];
    gemm8p<<<dim3(NB0), 256, 0, stream>>>(sa);
    sa.s[0] = {h0g, B_gw1, gb1, h1g, nullptr, nullptr, nullptr, 512, 1024, 2, 0, 0, 0};
    gemm8p<<<dim3(NB1), 256, 0, stream>>>(sa);
    sa.s[0] = {h1g, B_gw2, gb2, h2g, nullptr, nullptr, nullptr, 256, 512, 1, 1, 0, 0};
    gemm8p<<<dim3(NB2), 256, 0, stream>>>(sa);
    gate3_softmax<<<dim3(2048), 256, 0, stream>>>(h2g, gw3, gb3, wts);
    for (int e = 0; e < 8; e++) runGroup(e, 1, false);
  } else {
    bool first = true;
    for (int e0 = 0; e0 < 8; ){
      int cnt = (8 - e0 < G) ? (8 - e0) : G;
      runGroup(e0, cnt, first);
      first = false;
      e0 += cnt;
    }
  }

  combine<<<dim3(8192 / 256), 256, 0, stream>>>(wts, ret2, eb3, (float*)d_out);
}

// Round 14
// 477.830 us; speedup vs baseline: 1.3959x; 1.0798x over previous
//
#include <hip/hip_runtime.h>
#include <hip/hip_bf16.h>
#include <math.h>

// B=8192, D=512, V=64, E=8, hidden (1024,512,256)
// Round 14: R13 numerics (f16 split-A x single-f16 B) with 64-k steps —
// A tile [128][128] hi|lo (32KB), B tile [128][64] (16KB), both XOR-swizzled
// (source+read). Half the vmcnt/barrier events per K; two 32-MFMA clusters
// per step; stage(t+1) rides under the second cluster. 3 blocks/CU kept.

typedef _Float16 f16x8 __attribute__((ext_vector_type(8)));
typedef float f32x4 __attribute__((ext_vector_type(4)));

#define AS1 __attribute__((address_space(1)))
#define AS3 __attribute__((address_space(3)))
#define SCHED0 __builtin_amdgcn_sched_barrier(0)
#define SBAR __builtin_amdgcn_s_barrier()

__device__ __forceinline__ ushort h2u(_Float16 h){
  union { _Float16 h; ushort u; } v; v.h = h; return v.u;
}
__device__ __forceinline__ ushort h2u(__fp16 h){
  union { __fp16 h; ushort u; } v; v.h = h; return v.u;
}
__device__ __forceinline__ float elu_f(float x){
  return x > 0.f ? x : __expf(x) - 1.f;
}

// ---- unified prep: activations f32 [rows][K] -> [rows][2K] f16 hi|lo ----
struct AJob { const float* X; ushort* A; int total, K; };
__global__ void prep_act_all(AJob j0, AJob j1, int t0){
  int i = blockIdx.x * 256 + threadIdx.x;
  AJob J; int idx;
  if (i < t0){ J = j0; idx = i; }
  else { J = j1; idx = i - t0; if (idx >= J.total) return; }
  int row = idx / J.K, k = idx - row * J.K;
  float x = J.X[idx];
  _Float16 hi = (_Float16)x;                  // RN
  _Float16 lo = (_Float16)(x - (float)hi);
  size_t base = (size_t)row * (size_t)(2 * J.K);
  J.A[base + k] = h2u(hi);
  J.A[base + J.K + k] = h2u(lo);
}

// ---- unified prep: weights f32 [E][K][N] -> [E][N][K] single f16 ----
struct WJob { const float* W; ushort* Bt; int K, N, nb, nk, blkStart; };
struct WJobs { WJob j[6]; int njobs; };
__global__ void prep_w_all(WJobs jobs){
  __shared__ float tile[32][33];
  int b = blockIdx.x;
  int ji = 0;
  while (ji + 1 < jobs.njobs && b >= jobs.j[ji + 1].blkStart) ji++;
  WJob J = jobs.j[ji];
  int rem = b - J.blkStart;
  int x = rem % J.nb; rem /= J.nb;
  int y = rem % J.nk; int e = rem / J.nk;
  const float* w = J.W + (size_t)e * J.K * J.N;
  ushort* bt = J.Bt + (size_t)e * J.N * J.K;
  int n0 = x * 32, k0 = y * 32;
  for (int i = threadIdx.y; i < 32; i += 8)
    tile[i][threadIdx.x] = w[(size_t)(k0 + i) * J.N + n0 + threadIdx.x];
  __syncthreads();
  for (int jj = threadIdx.y; jj < 32; jj += 8){
    float v = tile[threadIdx.x][jj];
    bt[(size_t)(n0 + jj) * J.K + k0 + threadIdx.x] = h2u((_Float16)v);
  }
}

// ---- descriptor-batched 128x128 GEMM, f16 2-product, 64-k steps ----
// mode 0: C = split f16 [M][2N]; mode 1: C = f32 [M][N];
// mode 2: no C — ret[bx][row][eidx] = partial sum_col elu(acc+bias)*w3
struct Slice {
  const ushort* A; const ushort* Bt; const float* bias; void* C;
  const float* w3; const float* rbp; float* ret;
  int N, K, log2gx, mode, blkStart, eidx;
};
struct SliceArr { Slice s[9]; int nz; };

__global__ __launch_bounds__(256, 3) void gemm8p(SliceArr args){
  // A tile [128][128]: cols 0..63 = hi k0..63, cols 64..127 = lo (32KB)
  // B tile [128][64]:  single f16 k0..63 (16KB)
  __shared__ __align__(16) ushort As[128][128];
  __shared__ __align__(16) ushort Bs[128][64];
  __shared__ float red[2][128];

  // XCD-chunked bijective swizzle (grids here are multiples of 8)
  const int nwg  = gridDim.x;
  const int orig = blockIdx.x;
  const int wg   = (orig & 7) * (nwg >> 3) + (orig >> 3);

  int z = 0;
  while (z + 1 < args.nz && wg >= args.s[z + 1].blkStart) z++;
  const Slice sl = args.s[z];
  const int rem = wg - sl.blkStart;
  const int gxm = (1 << sl.log2gx) - 1;
  const int bx  = rem & gxm;
  const int by  = rem >> sl.log2gx;

  const ushort* __restrict__ Ag = sl.A;
  const ushort* __restrict__ Bg = sl.Bt;
  const int K = sl.K;

  const int tid  = threadIdx.x;
  const int lane = tid & 63;
  const int wave = tid >> 6;                    // 0..3
  const int wr = wave >> 1;                     // 0..1 : rows wr*64..+63
  const int wc = wave & 1;                      // 0..1 : cols wc*64..+63
  const int rowBase = by * 128;
  const int colBase = bx * 128;
  const int KB = K >> 6;                        // 64-k steps
  const int lr = lane & 15;
  const int lk = (lane >> 4) << 3;
  const int swzR = (lr & 7) << 3;
  const size_t strideK2 = (size_t)(2 * K);      // A stride (hi|lo)

  // staging constants (swizzle on source col, linear dest)
  const int rA = tid >> 4;                      // 0..15 (+j*16)
  const int cSA = (((tid & 15) << 3)) ^ ((rA & 7) << 3);   // kind bit 6 kept
  const int rB = tid >> 3;                      // 0..31 (+j*32)
  const int cSB = (((tid & 7) << 3)) ^ ((rB & 7) << 3);

  // stage A (32KB, 8 instrs) + B (16KB, 4 instrs) of 64-k step kt
  auto stage = [&](int kt){
    int tt = (kt < KB) ? kt : (KB - 1);         // clamp: dead-but-safe
    int kA = ((cSA & 64) ? K : 0) + (tt << 6) + (cSA & 63);
    {
      char* lb = (char*)&As[0][0];
      #pragma unroll
      for (int j = 0; j < 8; j++){
        const ushort* src = Ag + (size_t)(rowBase + j * 16 + rA) * strideK2 + kA;
        __builtin_amdgcn_global_load_lds((const AS1 void*)src,
                                         (AS3 void*)(lb + j * 4096 + tid * 16), 16, 0, 0);
      }
    }
    int kB = (tt << 6) + cSB;
    {
      char* lb = (char*)&Bs[0][0];
      #pragma unroll
      for (int j = 0; j < 4; j++){
        const ushort* src = Bg + (size_t)(colBase + j * 32 + rB) * (size_t)K + kB;
        __builtin_amdgcn_global_load_lds((const AS1 void*)src,
                                         (AS3 void*)(lb + j * 4096 + tid * 16), 16, 0, 0);
      }
    }
  };

  f16x8 ah[4], al[4], bv[4];
  auto readKs = [&](int ks){
    int kc = (ks << 5) + lk;                    // 0..63 within k-space
    #pragma unroll
    for (int n = 0; n < 4; n++)
      bv[n] = *(const f16x8*)&Bs[wc * 64 + n * 16 + lr][kc ^ swzR];
    #pragma unroll
    for (int m = 0; m < 4; m++){
      ah[m] = *(const f16x8*)&As[wr * 64 + m * 16 + lr][kc ^ swzR];
      al[m] = *(const f16x8*)&As[wr * 64 + m * 16 + lr][64 + (kc ^ swzR)];
    }
  };

  f32x4 acc[4][4];
  #pragma unroll
  for (int m = 0; m < 4; m++)
    #pragma unroll
    for (int n = 0; n < 4; n++)
      acc[m][n] = (f32x4){0.f, 0.f, 0.f, 0.f};

  auto mfmaC = [&](){
    #pragma unroll
    for (int m = 0; m < 4; m++)
      #pragma unroll
      for (int n = 0; n < 4; n++){
        f32x4 c = acc[m][n];
        c = __builtin_amdgcn_mfma_f32_16x16x32_f16(al[m], bv[n], c, 0, 0, 0);
        c = __builtin_amdgcn_mfma_f32_16x16x32_f16(ah[m], bv[n], c, 0, 0, 0);
        acc[m][n] = c;
      }
  };

  // prologue
  stage(0);

  for (int t = 0; t < KB; ++t){
    asm volatile("s_waitcnt vmcnt(0)" ::: "memory");  // tile t landed
    SCHED0; SBAR; SCHED0;
    readKs(0);
    asm volatile("s_waitcnt lgkmcnt(0)" ::: "memory"); SCHED0;
    __builtin_amdgcn_s_setprio(1); mfmaC(); __builtin_amdgcn_s_setprio(0);
    SCHED0;
    readKs(1);
    asm volatile("s_waitcnt lgkmcnt(0)" ::: "memory"); SCHED0;
    SBAR; SCHED0;                                     // all reads done blockwide
    stage(t + 1); SCHED0;                             // DMA rides under MFMA
    __builtin_amdgcn_s_setprio(1); mfmaC(); __builtin_amdgcn_s_setprio(0);
    SCHED0;
  }
  asm volatile("s_waitcnt vmcnt(0)" ::: "memory");    // drain dead last stage

  // ---- epilogue ----
  // acc[m][n]: row = rowBase + wr*64 + m*16 + (lane>>4)*4 + r
  //            col = colBase + wc*64 + n*16 + lr
  if (sl.mode == 2){
    __syncthreads();
    #pragma unroll
    for (int m = 0; m < 4; m++){
      float p4[4] = {0.f, 0.f, 0.f, 0.f};
      #pragma unroll
      for (int n = 0; n < 4; n++){
        int col = colBase + wc * 64 + n * 16 + lr;
        float bv2 = sl.bias[col];
        float wv = sl.w3[col];
        #pragma unroll
        for (int r = 0; r < 4; r++)
          p4[r] += elu_f(acc[m][n][r] + bv2) * wv;
      }
      #pragma unroll
      for (int r = 0; r < 4; r++){
        #pragma unroll
        for (int s = 8; s > 0; s >>= 1) p4[r] += __shfl_xor(p4[r], s, 64);
      }
      if ((lane & 15) == 0){
        int hig = lane >> 4;
        int rowoff = wr * 64 + m * 16 + hig * 4;
        #pragma unroll
        for (int r = 0; r < 4; r++)
          red[wc][rowoff + r] = p4[r];
      }
    }
    __syncthreads();
    if (tid < 128){
      float s2 = red[0][tid] + red[1][tid];
      sl.ret[((size_t)bx * 8192 + rowBase + tid) * 8 + sl.eidx] = s2;  // bias in combine
    }
    return;
  }

  const int N = sl.N;
  #pragma unroll
  for (int m = 0; m < 4; m++){
    int row0 = rowBase + wr * 64 + m * 16 + ((lane >> 4) << 2);
    #pragma unroll
    for (int n = 0; n < 4; n++){
      int col = colBase + wc * 64 + n * 16 + lr;
      float bv2 = sl.bias[col];
      float v0 = elu_f(acc[m][n][0] + bv2);
      float v1 = elu_f(acc[m][n][1] + bv2);
      float v2 = elu_f(acc[m][n][2] + bv2);
      float v3 = elu_f(acc[m][n][3] + bv2);
      if (sl.mode == 0){
        auto hp01 = __builtin_amdgcn_cvt_pkrtz(v0, v1);
        auto hp23 = __builtin_amdgcn_cvt_pkrtz(v2, v3);
        auto lp01 = __builtin_amdgcn_cvt_pkrtz(v0 - (float)hp01[0], v1 - (float)hp01[1]);
        auto lp23 = __builtin_amdgcn_cvt_pkrtz(v2 - (float)hp23[0], v3 - (float)hp23[1]);
        ushort* C = (ushort*)sl.C;
        size_t s2n = (size_t)(2 * N);
        size_t r0b = (size_t)row0 * s2n + col;
        C[r0b]            = h2u(hp01[0]);
        C[r0b + s2n]      = h2u(hp01[1]);
        C[r0b + 2 * s2n]  = h2u(hp23[0]);
        C[r0b + 3 * s2n]  = h2u(hp23[1]);
        size_t r0l = r0b + N;
        C[r0l]            = h2u(lp01[0]);
        C[r0l + s2n]      = h2u(lp01[1]);
        C[r0l + 2 * s2n]  = h2u(lp23[0]);
        C[r0l + 3 * s2n]  = h2u(lp23[1]);
      } else {
        float* C = (float*)sl.C;
        size_t r0b = (size_t)row0 * N + col;
        C[r0b]         = v0;
        C[r0b + N]     = v1;
        C[r0b + 2 * N] = v2;
        C[r0b + 3 * N] = v3;
      }
    }
  }
}

// ---- gate final layer + softmax ----
__global__ void gate3_softmax(const float* __restrict__ g2, const float* __restrict__ gw3,
                              const float* __restrict__ gb3, float* __restrict__ wts){
  int row = blockIdx.x * 4 + (threadIdx.x >> 6);
  int lane = threadIdx.x & 63;
  const float* g = g2 + (size_t)row * 256;
  float p[8];
  #pragma unroll
  for (int j = 0; j < 8; j++) p[j] = 0.f;
  for (int k = lane; k < 256; k += 64){
    float x = g[k];
    #pragma unroll
    for (int j = 0; j < 8; j++) p[j] += x * gw3[k * 8 + j];
  }
  #pragma unroll
  for (int j = 0; j < 8; j++){
    #pragma unroll
    for (int s = 32; s > 0; s >>= 1) p[j] += __shfl_xor(p[j], s, 64);
  }
  float mx = -1e30f;
  #pragma unroll
  for (int j = 0; j < 8; j++){ p[j] += gb3[j]; mx = fmaxf(mx, p[j]); }
  float sum = 0.f;
  #pragma unroll
  for (int j = 0; j < 8; j++){ p[j] = expf(p[j] - mx); sum += p[j]; }
  float inv = 1.f / sum;
  #pragma unroll
  for (int j = 0; j < 8; j++)
    if (lane == j) wts[(size_t)row * 8 + j] = p[j] * inv;
}

// ---- final combine: ret2 holds two col-half partials; add eb3 here ----
__global__ void combine(const float* __restrict__ wts, const float* __restrict__ ret2,
                        const float* __restrict__ eb3, float* __restrict__ out){
  int i = blockIdx.x * blockDim.x + threadIdx.x;
  if (i >= 8192) return;
  float s = 0.f;
  #pragma unroll
  for (int j = 0; j < 8; j++){
    float r = ret2[(size_t)i * 8 + j] + ret2[65536 + (size_t)i * 8 + j] + eb3[j];
    s += wts[(size_t)i * 8 + j] * r;
  }
  out[i] = s;
}

extern "C" void kernel_launch(void* const* d_in, const int* in_sizes, int n_in,
                              void* d_out, int out_size, void* d_ws, size_t ws_size,
                              hipStream_t stream){
  const float* obs  = (const float*)d_in[0];
  const float* code = (const float*)d_in[1];
  const float* ew0  = (const float*)d_in[2];
  const float* eb0  = (const float*)d_in[3];
  const float* ew1  = (const float*)d_in[4];
  const float* eb1  = (const float*)d_in[5];
  const float* ew2  = (const float*)d_in[6];
  const float* eb2  = (const float*)d_in[7];
  const float* ew3  = (const float*)d_in[8];
  const float* eb3  = (const float*)d_in[9];
  const float* gw0  = (const float*)d_in[10];
  const float* gb0  = (const float*)d_in[11];
  const float* gw1  = (const float*)d_in[12];
  const float* gb1  = (const float*)d_in[13];
  const float* gw2  = (const float*)d_in[14];
  const float* gb2  = (const float*)d_in[15];
  const float* gw3  = (const float*)d_in[16];
  const float* gb3  = (const float*)d_in[17];
  (void)in_sizes; (void)n_in; (void)out_size;

  char* ws = (char*)d_ws;
  size_t off = 0;
  auto alloc = [&](size_t bytes) -> void* {
    void* p = ws + off;
    off += (bytes + 255) & ~(size_t)255;
    return p;
  };
  ushort* A_obs  = (ushort*)alloc(8192ull * 1024 * 2);     // [8192][2*512] f16
  ushort* A_code = (ushort*)alloc(8192ull * 128 * 2);      // [8192][2*64] f16
  ushort* B_ew0  = (ushort*)alloc(8ull * 1024 * 512 * 2);  // [8][1024][512] f16
  ushort* B_ew1  = (ushort*)alloc(8ull * 512 * 1024 * 2);
  ushort* B_ew2  = (ushort*)alloc(8ull * 256 * 512 * 2);
  ushort* B_gw0  = (ushort*)alloc(1024ull * 64 * 2);
  ushort* B_gw1  = (ushort*)alloc(512ull * 1024 * 2);
  ushort* B_gw2  = (ushort*)alloc(256ull * 512 * 2);
  float*  wts    = (float*)alloc(8192ull * 8 * 4);
  float*  ret2   = (float*)alloc(2ull * 8192 * 8 * 4);
  const size_t fixed = off;

  const size_t sl0b = 8192ull * 2048 * 2;   // h0 split f16 (32MiB)
  const size_t sl1b = 8192ull * 1024 * 2;   // h1 split f16 (16MiB)
  const size_t pairB = sl0b + sl1b;

  int G = 0;
  {
    const int cand[5] = {8, 4, 3, 2, 1};
    for (int ci = 0; ci < 5; ci++)
      if (fixed + (size_t)(cand[ci] + 1) * pairB <= ws_size){ G = cand[ci]; break; }
  }
  const bool gateFirst = (G == 0);
  const int ns = gateFirst ? 1 : (G + 1);
  ushort* h0buf = (ushort*)alloc((size_t)ns * sl0b);
  ushort* h1buf = (ushort*)alloc((size_t)ns * sl1b);
  const size_t sl0e = 8192ull * 2048;
  const size_t sl1e = 8192ull * 1024;
  const int gsl = ns - 1;
  ushort* h0g = h0buf + (size_t)gsl * sl0e;
  ushort* h1g = h1buf + (size_t)gsl * sl1e;
  float*  h2g = (float*)h0g;                 // alias: h0g dead after gate L1

  // prep (2 dispatches)
  {
    AJob j0 = {obs,  A_obs,  8192 * 512, 512};
    AJob j1 = {code, A_code, 8192 * 64,  64};
    int t0 = 8192 * 512;
    prep_act_all<<<dim3((t0 + j1.total + 255) / 256), 256, 0, stream>>>(j0, j1, t0);

    WJobs wj; wj.njobs = 6;
    int bs = 0;
    auto addW = [&](int i, const float* W, ushort* Bt, int K, int N, int E){
      wj.j[i] = {W, Bt, K, N, N / 32, K / 32, bs};
      bs += E * (N / 32) * (K / 32);
    };
    addW(0, ew0, B_ew0, 512, 1024, 8);
    addW(1, ew1, B_ew1, 1024, 512, 8);
    addW(2, ew2, B_ew2, 512, 256, 8);
    addW(3, gw0, B_gw0, 64, 1024, 1);
    addW(4, gw1, B_gw1, 1024, 512, 1);
    addW(5, gw2, B_gw2, 512, 256, 1);
    prep_w_all<<<dim3(bs), dim3(32, 8), 0, stream>>>(wj);
  }

  // per-slice block counts at 128x128 tiles (gy = 64)
  const int NB0 = 8 * 64;    // L0: N=1024 -> 512
  const int NB1 = 4 * 64;    // L1: N=512  -> 256
  const int NB2 = 2 * 64;    // L2: N=256  -> 128

  auto runGroup = [&](int e0, int cnt, bool withGate){
    SliceArr sa; int nb;
    // L0
    nb = 0; sa.nz = cnt + (withGate ? 1 : 0);
    for (int i = 0; i < cnt; i++){ int e = e0 + i;
      sa.s[i] = {A_obs, B_ew0 + (size_t)e * 1024 * 512, eb0 + e * 1024,
                 h0buf + (size_t)i * sl0e, nullptr, nullptr, nullptr,
                 1024, 512, 3, 0, nb, 0};
      nb += NB0;
    }
    if (withGate){
      sa.s[cnt] = {A_code, B_gw0, gb0, h0g, nullptr, nullptr, nullptr,
                   1024, 64, 3, 0, nb, 0};
      nb += NB0;
    }
    for (int i = sa.nz; i < 9; i++) sa.s[i] = sa.s[0];
    gemm8p<<<dim3(nb), 256, 0, stream>>>(sa);
    // L1
    nb = 0;
    for (int i = 0; i < cnt; i++){ int e = e0 + i;
      sa.s[i] = {h0buf + (size_t)i * sl0e, B_ew1 + (size_t)e * 512 * 1024, eb1 + e * 512,
                 h1buf + (size_t)i * sl1e, nullptr, nullptr, nullptr,
                 512, 1024, 2, 0, nb, 0};
      nb += NB1;
    }
    if (withGate){
      sa.s[cnt] = {h0g, B_gw1, gb1, h1g, nullptr, nullptr, nullptr,
                   512, 1024, 2, 0, nb, 0};
      nb += NB1;
    }
    gemm8p<<<dim3(nb), 256, 0, stream>>>(sa);
    // L2: experts fused-returns partials (mode 2); gate f32 h2 (mode 1)
    nb = 0;
    for (int i = 0; i < cnt; i++){ int e = e0 + i;
      sa.s[i] = {h1buf + (size_t)i * sl1e, B_ew2 + (size_t)e * 256 * 512, eb2 + e * 256,
                 nullptr, ew3 + (size_t)e * 256, eb3 + e, ret2,
                 256, 512, 1, 2, nb, e};
      nb += NB2;
    }
    if (withGate){
      sa.s[cnt] = {h1g, B_gw2, gb2, h2g, nullptr, nullptr, nullptr,
                   256, 512, 1, 1, nb, 0};
      nb += NB2;
    }
    gemm8p<<<dim3(nb), 256, 0, stream>>>(sa);
    if (withGate)
      gate3_softmax<<<dim3(2048), 256, 0, stream>>>(h2g, gw3, gb3, wts);
  };

  if (gateFirst){
    SliceArr sa; sa.nz = 1;
    sa.s[0] = {A_code, B_gw0, gb0, h0g, nullptr, nullptr, nullptr, 1024, 64, 3, 0, 0, 0};
    for (int i = 1; i < 9; i++) sa.s[i] = sa.s[0];
    gemm8p<<<dim3(NB0), 256, 0, stream>>>(sa);
    sa.s[0] = {h0g, B_gw1, gb1, h1g, nullptr, nullptr, nullptr, 512, 1024, 2, 0, 0, 0};
    gemm8p<<<dim3(NB1), 256, 0, stream>>>(sa);
    sa.s[0] = {h1g, B_gw2, gb2, h2g, nullptr, nullptr, nullptr, 256, 512, 1, 1, 0, 0};
    gemm8p<<<dim3(NB2), 256, 0, stream>>>(sa);
    gate3_softmax<<<dim3(2048), 256, 0, stream>>>(h2g, gw3, gb3, wts);
    for (int e = 0; e < 8; e++) runGroup(e, 1, false);
  } else {
    bool first = true;
    for (int e0 = 0; e0 < 8; ){
      int cnt = (8 - e0 < G) ? (8 - e0) : G;
      runGroup(e0, cnt, first);
      first = false;
      e0 += cnt;
    }
  }

  combine<<<dim3(8192 / 256), 256, 0, stream>>>(wts, ret2, eb3, (float*)d_out);
}

// Round 15
// 287.102 us; speedup vs baseline: 2.3232x; 1.6643x over previous
//
#include <hip/hip_runtime.h>
#include <hip/hip_bf16.h>
#include <math.h>

// B=8192, D=512, V=64, E=8, hidden (1024,512,256)
// Round 15: single-f16 A x single-f16 B (1 MFMA per fragment; error budget
// audit: absmax 4.88e-4 -> ~1e-3 vs threshold 2.27e-3). Both tiles use the
// R10-proven [128][64] XOR-swizzled layout (0 bank conflicts measured).
// 64-k steps, 32KB staged/step, 33.5KB LDS -> 4 blocks/CU. Intermediate
// activations stored as single f16 with RN (not RTZ).

typedef _Float16 f16x8 __attribute__((ext_vector_type(8)));
typedef float f32x4 __attribute__((ext_vector_type(4)));

#define AS1 __attribute__((address_space(1)))
#define AS3 __attribute__((address_space(3)))
#define SCHED0 __builtin_amdgcn_sched_barrier(0)
#define SBAR __builtin_amdgcn_s_barrier()

__device__ __forceinline__ ushort h2u(_Float16 h){
  union { _Float16 h; ushort u; } v; v.h = h; return v.u;
}
__device__ __forceinline__ float elu_f(float x){
  return x > 0.f ? x : __expf(x) - 1.f;
}

// ---- unified prep: activations f32 -> single f16 (RN) ----
struct AJob { const float* X; ushort* A; int total; };
__global__ void prep_act_all(AJob j0, AJob j1, int t0){
  int i = blockIdx.x * 256 + threadIdx.x;
  AJob J; int idx;
  if (i < t0){ J = j0; idx = i; }
  else { J = j1; idx = i - t0; if (idx >= J.total) return; }
  J.A[idx] = h2u((_Float16)J.X[idx]);
}

// ---- unified prep: weights f32 [E][K][N] -> [E][N][K] single f16 ----
struct WJob { const float* W; ushort* Bt; int K, N, nb, nk, blkStart; };
struct WJobs { WJob j[6]; int njobs; };
__global__ void prep_w_all(WJobs jobs){
  __shared__ float tile[32][33];
  int b = blockIdx.x;
  int ji = 0;
  while (ji + 1 < jobs.njobs && b >= jobs.j[ji + 1].blkStart) ji++;
  WJob J = jobs.j[ji];
  int rem = b - J.blkStart;
  int x = rem % J.nb; rem /= J.nb;
  int y = rem % J.nk; int e = rem / J.nk;
  const float* w = J.W + (size_t)e * J.K * J.N;
  ushort* bt = J.Bt + (size_t)e * J.N * J.K;
  int n0 = x * 32, k0 = y * 32;
  for (int i = threadIdx.y; i < 32; i += 8)
    tile[i][threadIdx.x] = w[(size_t)(k0 + i) * J.N + n0 + threadIdx.x];
  __syncthreads();
  for (int jj = threadIdx.y; jj < 32; jj += 8){
    float v = tile[threadIdx.x][jj];
    bt[(size_t)(n0 + jj) * J.K + k0 + threadIdx.x] = h2u((_Float16)v);
  }
}

// ---- descriptor-batched 128x128 GEMM, single-f16, 64-k steps ----
// mode 0: C = f16 [M][N]; mode 1: C = f32 [M][N];
// mode 2: no C — ret[bx][row][eidx] = partial sum_col elu(acc+bias)*w3
struct Slice {
  const ushort* A; const ushort* Bt; const float* bias; void* C;
  const float* w3; const float* rbp; float* ret;
  int N, K, log2gx, mode, blkStart, eidx;
};
struct SliceArr { Slice s[9]; int nz; };

__global__ __launch_bounds__(256, 3) void gemm8p(SliceArr args){
  // A,B tiles [128][64] f16 (16KB each), cols = k 0..63, XOR-swizzled
  __shared__ __align__(16) ushort As[128][64];
  __shared__ __align__(16) ushort Bs[128][64];
  __shared__ float red[2][128];

  // XCD-chunked bijective swizzle (grids here are multiples of 8)
  const int nwg  = gridDim.x;
  const int orig = blockIdx.x;
  const int wg   = (orig & 7) * (nwg >> 3) + (orig >> 3);

  int z = 0;
  while (z + 1 < args.nz && wg >= args.s[z + 1].blkStart) z++;
  const Slice sl = args.s[z];
  const int rem = wg - sl.blkStart;
  const int gxm = (1 << sl.log2gx) - 1;
  const int bx  = rem & gxm;
  const int by  = rem >> sl.log2gx;

  const ushort* __restrict__ Ag = sl.A;
  const ushort* __restrict__ Bg = sl.Bt;
  const int K = sl.K;

  const int tid  = threadIdx.x;
  const int lane = tid & 63;
  const int wave = tid >> 6;                    // 0..3
  const int wr = wave >> 1;                     // 0..1 : rows wr*64..+63
  const int wc = wave & 1;                      // 0..1 : cols wc*64..+63
  const int rowBase = by * 128;
  const int colBase = bx * 128;
  const int KB = K >> 6;                        // 64-k steps
  const int lr = lane & 15;
  const int lk = (lane >> 4) << 3;
  const int swzR = (lr & 7) << 3;

  // staging constants: 4 instrs per tile; rows j*32+rS, source col swizzled
  const int rS = tid >> 3;                      // 0..31
  const int cS = ((tid & 7) << 3) ^ ((rS & 7) << 3);

  // stage A (16KB) + B (16KB) of 64-k step kt (8 instrs/thread)
  auto stage = [&](int kt){
    int tt = (kt < KB) ? kt : (KB - 1);         // clamp: dead-but-safe
    int kc = (tt << 6) + cS;
    {
      char* lb = (char*)&As[0][0];
      #pragma unroll
      for (int j = 0; j < 4; j++){
        const ushort* src = Ag + (size_t)(rowBase + j * 32 + rS) * (size_t)K + kc;
        __builtin_amdgcn_global_load_lds((const AS1 void*)src,
                                         (AS3 void*)(lb + j * 4096 + tid * 16), 16, 0, 0);
      }
    }
    {
      char* lb = (char*)&Bs[0][0];
      #pragma unroll
      for (int j = 0; j < 4; j++){
        const ushort* src = Bg + (size_t)(colBase + j * 32 + rS) * (size_t)K + kc;
        __builtin_amdgcn_global_load_lds((const AS1 void*)src,
                                         (AS3 void*)(lb + j * 4096 + tid * 16), 16, 0, 0);
      }
    }
  };

  f16x8 av[4], bv[4];
  auto readKs = [&](int ks){
    int kc = (ks << 5) + lk;                    // 0..63
    #pragma unroll
    for (int n = 0; n < 4; n++)
      bv[n] = *(const f16x8*)&Bs[wc * 64 + n * 16 + lr][kc ^ swzR];
    #pragma unroll
    for (int m = 0; m < 4; m++)
      av[m] = *(const f16x8*)&As[wr * 64 + m * 16 + lr][kc ^ swzR];
  };

  f32x4 acc[4][4];
  #pragma unroll
  for (int m = 0; m < 4; m++)
    #pragma unroll
    for (int n = 0; n < 4; n++)
      acc[m][n] = (f32x4){0.f, 0.f, 0.f, 0.f};

  auto mfmaC = [&](){
    #pragma unroll
    for (int m = 0; m < 4; m++)
      #pragma unroll
      for (int n = 0; n < 4; n++)
        acc[m][n] = __builtin_amdgcn_mfma_f32_16x16x32_f16(av[m], bv[n], acc[m][n], 0, 0, 0);
  };

  // prologue
  stage(0);

  for (int t = 0; t < KB; ++t){
    asm volatile("s_waitcnt vmcnt(0)" ::: "memory");  // tile t landed
    SCHED0; SBAR; SCHED0;
    readKs(0);
    asm volatile("s_waitcnt lgkmcnt(0)" ::: "memory"); SCHED0;
    __builtin_amdgcn_s_setprio(1); mfmaC(); __builtin_amdgcn_s_setprio(0);
    SCHED0;
    readKs(1);
    asm volatile("s_waitcnt lgkmcnt(0)" ::: "memory"); SCHED0;
    SBAR; SCHED0;                                     // all reads done blockwide
    stage(t + 1); SCHED0;                             // DMA rides under MFMA
    __builtin_amdgcn_s_setprio(1); mfmaC(); __builtin_amdgcn_s_setprio(0);
    SCHED0;
  }
  asm volatile("s_waitcnt vmcnt(0)" ::: "memory");    // drain dead last stage

  // ---- epilogue ----
  // acc[m][n]: row = rowBase + wr*64 + m*16 + (lane>>4)*4 + r
  //            col = colBase + wc*64 + n*16 + lr
  if (sl.mode == 2){
    __syncthreads();
    #pragma unroll
    for (int m = 0; m < 4; m++){
      float p4[4] = {0.f, 0.f, 0.f, 0.f};
      #pragma unroll
      for (int n = 0; n < 4; n++){
        int col = colBase + wc * 64 + n * 16 + lr;
        float bv2 = sl.bias[col];
        float wv = sl.w3[col];
        #pragma unroll
        for (int r = 0; r < 4; r++)
          p4[r] += elu_f(acc[m][n][r] + bv2) * wv;
      }
      #pragma unroll
      for (int r = 0; r < 4; r++){
        #pragma unroll
        for (int s = 8; s > 0; s >>= 1) p4[r] += __shfl_xor(p4[r], s, 64);
      }
      if ((lane & 15) == 0){
        int hig = lane >> 4;
        int rowoff = wr * 64 + m * 16 + hig * 4;
        #pragma unroll
        for (int r = 0; r < 4; r++)
          red[wc][rowoff + r] = p4[r];
      }
    }
    __syncthreads();
    if (tid < 128){
      float s2 = red[0][tid] + red[1][tid];
      sl.ret[((size_t)bx * 8192 + rowBase + tid) * 8 + sl.eidx] = s2;  // bias in combine
    }
    return;
  }

  const int N = sl.N;
  #pragma unroll
  for (int m = 0; m < 4; m++){
    int row0 = rowBase + wr * 64 + m * 16 + ((lane >> 4) << 2);
    #pragma unroll
    for (int n = 0; n < 4; n++){
      int col = colBase + wc * 64 + n * 16 + lr;
      float bv2 = sl.bias[col];
      float v0 = elu_f(acc[m][n][0] + bv2);
      float v1 = elu_f(acc[m][n][1] + bv2);
      float v2 = elu_f(acc[m][n][2] + bv2);
      float v3 = elu_f(acc[m][n][3] + bv2);
      if (sl.mode == 0){
        ushort* C = (ushort*)sl.C;
        size_t r0b = (size_t)row0 * N + col;
        C[r0b]         = h2u((_Float16)v0);   // RN, not RTZ
        C[r0b + N]     = h2u((_Float16)v1);
        C[r0b + 2 * N] = h2u((_Float16)v2);
        C[r0b + 3 * N] = h2u((_Float16)v3);
      } else {
        float* C = (float*)sl.C;
        size_t r0b = (size_t)row0 * N + col;
        C[r0b]         = v0;
        C[r0b + N]     = v1;
        C[r0b + 2 * N] = v2;
        C[r0b + 3 * N] = v3;
      }
    }
  }
}

// ---- gate final layer + softmax ----
__global__ void gate3_softmax(const float* __restrict__ g2, const float* __restrict__ gw3,
                              const float* __restrict__ gb3, float* __restrict__ wts){
  int row = blockIdx.x * 4 + (threadIdx.x >> 6);
  int lane = threadIdx.x & 63;
  const float* g = g2 + (size_t)row * 256;
  float p[8];
  #pragma unroll
  for (int j = 0; j < 8; j++) p[j] = 0.f;
  for (int k = lane; k < 256; k += 64){
    float x = g[k];
    #pragma unroll
    for (int j = 0; j < 8; j++) p[j] += x * gw3[k * 8 + j];
  }
  #pragma unroll
  for (int j = 0; j < 8; j++){
    #pragma unroll
    for (int s = 32; s > 0; s >>= 1) p[j] += __shfl_xor(p[j], s, 64);
  }
  float mx = -1e30f;
  #pragma unroll
  for (int j = 0; j < 8; j++){ p[j] += gb3[j]; mx = fmaxf(mx, p[j]); }
  float sum = 0.f;
  #pragma unroll
  for (int j = 0; j < 8; j++){ p[j] = expf(p[j] - mx); sum += p[j]; }
  float inv = 1.f / sum;
  #pragma unroll
  for (int j = 0; j < 8; j++)
    if (lane == j) wts[(size_t)row * 8 + j] = p[j] * inv;
}

// ---- final combine: ret2 holds two col-half partials; add eb3 here ----
__global__ void combine(const float* __restrict__ wts, const float* __restrict__ ret2,
                        const float* __restrict__ eb3, float* __restrict__ out){
  int i = blockIdx.x * blockDim.x + threadIdx.x;
  if (i >= 8192) return;
  float s = 0.f;
  #pragma unroll
  for (int j = 0; j < 8; j++){
    float r = ret2[(size_t)i * 8 + j] + ret2[65536 + (size_t)i * 8 + j] + eb3[j];
    s += wts[(size_t)i * 8 + j] * r;
  }
  out[i] = s;
}

extern "C" void kernel_launch(void* const* d_in, const int* in_sizes, int n_in,
                              void* d_out, int out_size, void* d_ws, size_t ws_size,
                              hipStream_t stream){
  const float* obs  = (const float*)d_in[0];
  const float* code = (const float*)d_in[1];
  const float* ew0  = (const float*)d_in[2];
  const float* eb0  = (const float*)d_in[3];
  const float* ew1  = (const float*)d_in[4];
  const float* eb1  = (const float*)d_in[5];
  const float* ew2  = (const float*)d_in[6];
  const float* eb2  = (const float*)d_in[7];
  const float* ew3  = (const float*)d_in[8];
  const float* eb3  = (const float*)d_in[9];
  const float* gw0  = (const float*)d_in[10];
  const float* gb0  = (const float*)d_in[11];
  const float* gw1  = (const float*)d_in[12];
  const float* gb1  = (const float*)d_in[13];
  const float* gw2  = (const float*)d_in[14];
  const float* gb2  = (const float*)d_in[15];
  const float* gw3  = (const float*)d_in[16];
  const float* gb3  = (const float*)d_in[17];
  (void)in_sizes; (void)n_in; (void)out_size;

  char* ws = (char*)d_ws;
  size_t off = 0;
  auto alloc = [&](size_t bytes) -> void* {
    void* p = ws + off;
    off += (bytes + 255) & ~(size_t)255;
    return p;
  };
  ushort* A_obs  = (ushort*)alloc(8192ull * 512 * 2);      // [8192][512] f16
  ushort* A_code = (ushort*)alloc(8192ull * 64 * 2);       // [8192][64] f16
  ushort* B_ew0  = (ushort*)alloc(8ull * 1024 * 512 * 2);  // [8][1024][512] f16
  ushort* B_ew1  = (ushort*)alloc(8ull * 512 * 1024 * 2);
  ushort* B_ew2  = (ushort*)alloc(8ull * 256 * 512 * 2);
  ushort* B_gw0  = (ushort*)alloc(1024ull * 64 * 2);
  ushort* B_gw1  = (ushort*)alloc(512ull * 1024 * 2);
  ushort* B_gw2  = (ushort*)alloc(256ull * 512 * 2);
  float*  wts    = (float*)alloc(8192ull * 8 * 4);
  float*  ret2   = (float*)alloc(2ull * 8192 * 8 * 4);
  const size_t fixed = off;

  const size_t sl0b = 8192ull * 1024 * 2;   // h0 single f16 (16.8MB)
  const size_t sl1b = 8192ull * 512 * 2;    // h1 single f16 (8.4MB)
  const size_t pairB = sl0b + sl1b;

  int G = 0;
  {
    const int cand[5] = {8, 4, 3, 2, 1};
    for (int ci = 0; ci < 5; ci++)
      if (fixed + (size_t)(cand[ci] + 1) * pairB <= ws_size){ G = cand[ci]; break; }
  }
  const bool gateFirst = (G == 0);
  const int ns = gateFirst ? 1 : (G + 1);
  ushort* h0buf = (ushort*)alloc((size_t)ns * sl0b);
  ushort* h1buf = (ushort*)alloc((size_t)ns * sl1b);
  const size_t sl0e = 8192ull * 1024;
  const size_t sl1e = 8192ull * 512;
  const int gsl = ns - 1;
  ushort* h0g = h0buf + (size_t)gsl * sl0e;
  ushort* h1g = h1buf + (size_t)gsl * sl1e;
  float*  h2g = (float*)h0g;                 // alias: h0g (16.8MB) >= h2 (8.4MB)

  // prep (2 dispatches)
  {
    AJob j0 = {obs,  A_obs,  8192 * 512};
    AJob j1 = {code, A_code, 8192 * 64};
    int t0 = 8192 * 512;
    prep_act_all<<<dim3((t0 + j1.total + 255) / 256), 256, 0, stream>>>(j0, j1, t0);

    WJobs wj; wj.njobs = 6;
    int bs = 0;
    auto addW = [&](int i, const float* W, ushort* Bt, int K, int N, int E){
      wj.j[i] = {W, Bt, K, N, N / 32, K / 32, bs};
      bs += E * (N / 32) * (K / 32);
    };
    addW(0, ew0, B_ew0, 512, 1024, 8);
    addW(1, ew1, B_ew1, 1024, 512, 8);
    addW(2, ew2, B_ew2, 512, 256, 8);
    addW(3, gw0, B_gw0, 64, 1024, 1);
    addW(4, gw1, B_gw1, 1024, 512, 1);
    addW(5, gw2, B_gw2, 512, 256, 1);
    prep_w_all<<<dim3(bs), dim3(32, 8), 0, stream>>>(wj);
  }

  // per-slice block counts at 128x128 tiles (gy = 64)
  const int NB0 = 8 * 64;    // L0: N=1024 -> 512
  const int NB1 = 4 * 64;    // L1: N=512  -> 256
  const int NB2 = 2 * 64;    // L2: N=256  -> 128

  auto runGroup = [&](int e0, int cnt, bool withGate){
    SliceArr sa; int nb;
    // L0
    nb = 0; sa.nz = cnt + (withGate ? 1 : 0);
    for (int i = 0; i < cnt; i++){ int e = e0 + i;
      sa.s[i] = {A_obs, B_ew0 + (size_t)e * 1024 * 512, eb0 + e * 1024,
                 h0buf + (size_t)i * sl0e, nullptr, nullptr, nullptr,
                 1024, 512, 3, 0, nb, 0};
      nb += NB0;
    }
    if (withGate){
      sa.s[cnt] = {A_code, B_gw0, gb0, h0g, nullptr, nullptr, nullptr,
                   1024, 64, 3, 0, nb, 0};
      nb += NB0;
    }
    for (int i = sa.nz; i < 9; i++) sa.s[i] = sa.s[0];
    gemm8p<<<dim3(nb), 256, 0, stream>>>(sa);
    // L1
    nb = 0;
    for (int i = 0; i < cnt; i++){ int e = e0 + i;
      sa.s[i] = {h0buf + (size_t)i * sl0e, B_ew1 + (size_t)e * 512 * 1024, eb1 + e * 512,
                 h1buf + (size_t)i * sl1e, nullptr, nullptr, nullptr,
                 512, 1024, 2, 0, nb, 0};
      nb += NB1;
    }
    if (withGate){
      sa.s[cnt] = {h0g, B_gw1, gb1, h1g, nullptr, nullptr, nullptr,
                   512, 1024, 2, 0, nb, 0};
      nb += NB1;
    }
    gemm8p<<<dim3(nb), 256, 0, stream>>>(sa);
    // L2: experts fused-returns partials (mode 2); gate f32 h2 (mode 1)
    nb = 0;
    for (int i = 0; i < cnt; i++){ int e = e0 + i;
      sa.s[i] = {h1buf + (size_t)i * sl1e, B_ew2 + (size_t)e * 256 * 512, eb2 + e * 256,
                 nullptr, ew3 + (size_t)e * 256, eb3 + e, ret2,
                 256, 512, 1, 2, nb, e};
      nb += NB2;
    }
    if (withGate){
      sa.s[cnt] = {h1g, B_gw2, gb2, h2g, nullptr, nullptr, nullptr,
                   256, 512, 1, 1, nb, 0};
      nb += NB2;
    }
    gemm8p<<<dim3(nb), 256, 0, stream>>>(sa);
    if (withGate)
      gate3_softmax<<<dim3(2048), 256, 0, stream>>>(h2g, gw3, gb3, wts);
  };

  if (gateFirst){
    SliceArr sa; sa.nz = 1;
    sa.s[0] = {A_code, B_gw0, gb0, h0g, nullptr, nullptr, nullptr, 1024, 64, 3, 0, 0, 0};
    for (int i = 1; i < 9; i++) sa.s[i] = sa.s[0];
    gemm8p<<<dim3(NB0), 256, 0, stream>>>(sa);
    sa.s[0] = {h0g, B_gw1, gb1, h1g, nullptr, nullptr, nullptr, 512, 1024, 2, 0, 0, 0};
    gemm8p<<<dim3(NB1), 256, 0, stream>>>(sa);
    sa.s[0] = {h1g, B_gw2, gb2, h2g, nullptr, nullptr, nullptr, 256, 512, 1, 1, 0, 0};
    gemm8p<<<dim3(NB2), 256, 0, stream>>>(sa);
    gate3_softmax<<<dim3(2048), 256, 0, stream>>>(h2g, gw3, gb3, wts);
    for (int e = 0; e < 8; e++) runGroup(e, 1, false);
  } else {
    bool first = true;
    for (int e0 = 0; e0 < 8; ){
      int cnt = (8 - e0 < G) ? (8 - e0) : G;
      runGroup(e0, cnt, first);
      first = false;
      e0 += cnt;
    }
  }

  combine<<<dim3(8192 / 256), 256, 0, stream>>>(wts, ret2, eb3, (float*)d_out);
}